// Round 22
// baseline (308.612 us; speedup 1.0000x reference)
//
#include <hip/hip_runtime.h>
#include <hip/hip_bf16.h>

#define TOKS 16384
#define HID  4096
#define NEXP 64
#define EPS  1e-4f   // flag threshold; trunc-split logit err ~6e-6 -> 16x margin

// ===== ws layout (floats) =====
// [0..63] prob sums | [64..127] argmax counts | int@[128] flag count |
// ints [192..192+16384) flag list | [16576) Bpack (1 MB) |
// [278720) Xhi (64M ushort) | [33833152) Xlo (64M ushort)   total ~270 MB
#define WS_FLAGCNT  128
#define WS_FLAGLIST 192
#define WS_BPACK    16576
#define WS_XHI      278720
#define WS_XLO      33833152

typedef __attribute__((ext_vector_type(8))) short short8_t;
typedef __attribute__((ext_vector_type(4))) float f32x4;

static __device__ __forceinline__ unsigned short f2bf_rn(float x) {
    unsigned u = __builtin_bit_cast(unsigned, x);
    u = (u + 0x7fffu + ((u >> 16) & 1u)) >> 16;
    return (unsigned short)u;
}
static __device__ __forceinline__ float bf2f(unsigned short h) {
    return __builtin_bit_cast(float, (unsigned)h << 16);
}
static __device__ __forceinline__ void gl2lds16(const void* g, void* l) {
    __builtin_amdgcn_global_load_lds(
        (const __attribute__((address_space(1))) unsigned int*)g,
        (__attribute__((address_space(3))) unsigned int*)l, 16, 0, 0);
}

// ---------- prep: W -> frag-packed bf16; (kt,nt) block = 2 KB: hi 1 KB | lo 1 KB ----------
__global__ void moe_prep(const float* __restrict__ W, unsigned short* __restrict__ Bpk,
                         float* __restrict__ wsf) {
    const int idx = blockIdx.x * blockDim.x + threadIdx.x;
    if (idx < 192) wsf[idx] = 0.0f;
    if (idx >= NEXP * HID) return;
    const int n = idx >> 12;
    const int k = idx & 4095;
    const float w = W[idx];
    const unsigned short hi = f2bf_rn(w);
    const unsigned short lo = f2bf_rn(w - bf2f(hi));
    const int kt   = k >> 5;
    const int nt   = n >> 4;
    const int lane = (n & 15) | (((k >> 3) & 3) << 4);
    const int j    = k & 7;
    const int dst  = (((kt << 2) + nt) << 10) + (lane << 3) + j;
    Bpk[dst]       = hi;
    Bpk[dst + 512] = lo;
}

// ---------- prepass: X fp32 -> pre-split bf16 hi/lo planes (pure BW) ----------
__global__ void moe_xcvt(const float* __restrict__ X, unsigned short* __restrict__ Xhi,
                         unsigned short* __restrict__ Xlo) {
    const size_t i = ((size_t)blockIdx.x * blockDim.x + threadIdx.x) << 2;
    const float4 v = *(const float4*)&X[i];
    ushort4 h, l;
    {
        unsigned u;
        u = __builtin_bit_cast(unsigned, v.x); h.x = (unsigned short)(u >> 16);
        l.x = (unsigned short)(__builtin_bit_cast(unsigned, v.x - bf2f(h.x)) >> 16);
        u = __builtin_bit_cast(unsigned, v.y); h.y = (unsigned short)(u >> 16);
        l.y = (unsigned short)(__builtin_bit_cast(unsigned, v.y - bf2f(h.y)) >> 16);
        u = __builtin_bit_cast(unsigned, v.z); h.z = (unsigned short)(u >> 16);
        l.z = (unsigned short)(__builtin_bit_cast(unsigned, v.z - bf2f(h.z)) >> 16);
        u = __builtin_bit_cast(unsigned, v.w); h.w = (unsigned short)(u >> 16);
        l.w = (unsigned short)(__builtin_bit_cast(unsigned, v.w - bf2f(h.w)) >> 16);
    }
    *(ushort4*)&Xhi[i] = h;
    *(ushort4*)&Xlo[i] = l;
}

// ---------- fused: producer/consumer, cvt-FREE consumer (pure ds_read + MFMA) ----------
// 256 blocks x 768 thr: waves 8..11 producers (gl_lds only), waves 0..7 consumers.
// X tiles staged CHUNK-MAJOR: [8 pos-columns][64 rows][16 B] per plane -> one 1 KB
// gl_lds per column; A-frag b128 reads are row-contiguous (2-way banks, free).
// 4-deep LDS (Xhi 8K + Xlo 8K + B 16K = 32 KB/buf, 128 KB), vmcnt(8), 1 barrier/step.
__global__ __launch_bounds__(768, 1)
void moe_fused(const unsigned short* __restrict__ Xhi, const unsigned short* __restrict__ Xlo,
               const unsigned short* __restrict__ Bpk,
               float* __restrict__ out, float* __restrict__ wsf) {
    __shared__ __align__(16) char xbuf[4][16384];  // [0,8K) hi cols, [8K,16K) lo cols
    __shared__ __align__(16) char bbuf[4][16384];  // 16 x 1 KB (ktl,nt,plane)
    float (*L)[68] = (float (*)[68])&xbuf[0][0];   // epilogue alias (17408 B)

    const int tid  = threadIdx.x;
    const int lane = tid & 63;
    const int w    = tid >> 6;                 // 0..11
    const int tok0 = blockIdx.x * 64;

    f32x4 acc[2];
    acc[0] = (f32x4){0.f, 0.f, 0.f, 0.f};
    acc[1] = (f32x4){0.f, 0.f, 0.f, 0.f};

    if (w >= 8) {
        // ================= PRODUCER =================
        const int p = w - 8;                   // 0..3; owns hi/lo cols 2p,2p+1 + 4 B chunks
        const size_t xrowoff = (size_t)(tok0 + lane) * HID;   // lane = row
        const char* BpkB = (const char*)Bpk;
        #define PSTAGE(bf, ss)                                                         \
        {                                                                              \
            const int k0_ = (ss) << 6;                                                 \
            _Pragma("unroll")                                                          \
            for (int j = 0; j < 2; ++j) {                                              \
                const int c = (p << 1) + j;                                            \
                gl2lds16(Xhi + xrowoff + k0_ + (c << 3),                               \
                         (void*)(&xbuf[bf][0] + (c << 10)));                           \
                gl2lds16(Xlo + xrowoff + k0_ + (c << 3),                               \
                         (void*)(&xbuf[bf][0] + 8192 + (c << 10)));                    \
            }                                                                          \
            _Pragma("unroll")                                                          \
            for (int j = 0; j < 4; ++j) {                                              \
                const int c1k = (p << 2) + j;                                          \
                gl2lds16(BpkB + ((size_t)(ss) << 14) + (c1k << 10) + (lane << 4),      \
                         (void*)(&bbuf[bf][0] + (c1k << 10)));                         \
            }                                                                          \
        }
        PSTAGE(0, 0);
        PSTAGE(1, 1);
        for (int s = 0; s < 64; ++s) {
            const int ss = (s + 2 < 64) ? (s + 2) : 63;   // tail dups land in dead bufs
            PSTAGE((s + 2) & 3, ss);
            asm volatile("s_waitcnt vmcnt(8)" ::: "memory");  // stage s+1 fully landed
            __builtin_amdgcn_s_barrier();
        }
        asm volatile("s_waitcnt vmcnt(0)" ::: "memory");
        #undef PSTAGE
    } else {
        // ================= CONSUMER (ZERO VALU in loop: ds_read + MFMA only) =========
        const int mt = w & 3;                  // m-tile (16 tokens)
        const int nh = w >> 2;                 // n-half (2 ntiles)
        const int g  = lane >> 4;
        const int arow16 = (((mt << 4) + (lane & 15)) << 4);  // row * 16 B
        for (int s = 0; s < 64; ++s) {
            __builtin_amdgcn_s_barrier();
            __builtin_amdgcn_sched_barrier(0);
            const int cur = s & 3;
            const char* xb = &xbuf[cur][0];
            const char* bb = &bbuf[cur][0];
            #pragma unroll
            for (int ktl = 0; ktl < 2; ++ktl) {
                const int cpos = ((ktl << 2) + g) << 10;      // chunk column base
                const short8_t ah = *(const short8_t*)(xb + cpos + arow16);
                const short8_t al = *(const short8_t*)(xb + 8192 + cpos + arow16);
                #pragma unroll
                for (int ntl = 0; ntl < 2; ++ntl) {
                    const char* bp = bb + (((ktl << 2) + (nh << 1) + ntl) << 11) + (lane << 4);
                    const short8_t bh = *(const short8_t*)bp;
                    const short8_t bl = *(const short8_t*)(bp + 1024);
                    acc[ntl] = __builtin_amdgcn_mfma_f32_16x16x32_bf16(ah, bh, acc[ntl], 0, 0, 0);
                    acc[ntl] = __builtin_amdgcn_mfma_f32_16x16x32_bf16(al, bh, acc[ntl], 0, 0, 0);
                    acc[ntl] = __builtin_amdgcn_mfma_f32_16x16x32_bf16(ah, bl, acc[ntl], 0, 0, 0);
                }
            }
            __builtin_amdgcn_sched_barrier(0);
        }
    }
    __syncthreads();   // all 12 waves; drains producer LDS writes

    // ---- logits -> L[token][expert] (L aliases xbuf; consumers only) ----
    if (w < 8) {
        const int mt = w & 3, nh = w >> 2, g = lane >> 4;
        #pragma unroll
        for (int ntl = 0; ntl < 2; ++ntl)
            #pragma unroll
            for (int rr = 0; rr < 4; ++rr)
                L[(mt << 4) + (g << 2) + rr][(nh << 5) + (ntl << 4) + (lane & 15)] = acc[ntl][rr];
    }
    __syncthreads();

    // ---- epilogue: consumer wave w handles tokens w*8 .. w*8+7; lane = expert ----
    float* outIdx = out;
    float* outW   = out + TOKS * 8;
    int* flagcnt  = (int*)wsf + WS_FLAGCNT;
    int* flaglist = (int*)wsf + WS_FLAGLIST;

    if (w < 8) {
        float rp = 0.f;
        #pragma unroll
        for (int tt = 0; tt < 8; ++tt) {
            const int tl = (w << 3) + tt;
            const float lg = L[tl][lane];

            // bitonic sort-64, descending by (value, then lower index first)
            float v = lg; int idx = lane;
            #pragma unroll
            for (int size = 2; size <= 64; size <<= 1) {
                #pragma unroll
                for (int str = size >> 1; str > 0; str >>= 1) {
                    const float ov = __shfl_xor(v, str, 64);
                    const int   oi = __shfl_xor(idx, str, 64);
                    const bool pb = (ov > v) || (ov == v && oi < idx);
                    const bool keepFirst = ((lane & str) == 0) == ((lane & size) == 0);
                    if (pb == keepFirst) { v = ov; idx = oi; }
                }
            }

            const float m = __shfl(v, 0, 64);
            const float p = __expf(lg - m);
            float sdenom = p;
            #pragma unroll
            for (int o = 32; o; o >>= 1) sdenom += __shfl_xor(sdenom, o, 64);
            const float inv_s = 1.0f / sdenom;
            rp += p * inv_s;

            const float wkv = __expf(v - m) * inv_s;
            float d8 = (lane < 8) ? wkv : 0.f;
            #pragma unroll
            for (int o = 1; o < 8; o <<= 1) d8 += __shfl_xor(d8, o, 64);
            const float invd = 1.0f / (d8 + 1e-20f);
            const float nv = __shfl_down(v, 1, 64);
            const bool flg = __any(lane < 8 && (v - nv) < EPS);

            const int gtok = tok0 + tl;
            if (lane < 8) {
                outIdx[(size_t)gtok * 8 + lane] = (float)idx;
                outW[(size_t)gtok * 8 + lane]   = wkv * invd;
            }
            if (lane == 0) {
                atomicAdd(&wsf[NEXP + idx], 1.0f);
                if (flg) {
                    const int pos = atomicAdd(flagcnt, 1);
                    if (pos < TOKS) flaglist[pos] = gtok;
                }
            }
        }
        atomicAdd(&wsf[lane], rp);
    }
}

// ---------- exact fp64 redo for flagged tokens (reads original fp32 X) ----------
__global__ __launch_bounds__(256, 2)
void moe_fix(const float* __restrict__ X, const float* __restrict__ W,
             float* __restrict__ out, float* __restrict__ wsf) {
    __shared__ double red[256];
    const int tid = threadIdx.x;
    const int e   = tid & 63;
    const int kc  = tid >> 6;
    const int nf  = min(*((int*)wsf + WS_FLAGCNT), TOKS);
    const int* flaglist = (const int*)wsf + WS_FLAGLIST;
    float* outIdx = out;
    float* outW   = out + TOKS * 8;

    for (int fi = blockIdx.x; fi < nf; fi += gridDim.x) {
        const int tok = flaglist[fi];
        const float* xrow = X + (size_t)tok * HID + kc * 1024;
        const float* wrow = W + (size_t)e  * HID + kc * 1024;
        double part = 0.0;
        for (int j = 0; j < 1024; j += 4) {
            const float4 xv = *(const float4*)(xrow + j);
            const float4 wv = *(const float4*)(wrow + j);
            part = fma((double)xv.x, (double)wv.x, part);
            part = fma((double)xv.y, (double)wv.y, part);
            part = fma((double)xv.z, (double)wv.z, part);
            part = fma((double)xv.w, (double)wv.w, part);
        }
        red[tid] = part;
        __syncthreads();
        if (tid < 64) {
            const double lg = ((red[tid] + red[64 + tid]) + red[128 + tid]) + red[192 + tid];
            const float lgf = (float)lg;
            float m = lgf;
            #pragma unroll
            for (int o = 32; o; o >>= 1) m = fmaxf(m, __shfl_xor(m, o, 64));
            const float p = __expf(lgf - m);
            float s = p;
            #pragma unroll
            for (int o = 32; o; o >>= 1) s += __shfl_xor(s, o, 64);
            const float inv_s = 1.0f / s;

            double v = lg;
            double bw[8]; int ik[8];
            #pragma unroll
            for (int k = 0; k < 8; ++k) {
                double bv = v; int bi = tid;
                #pragma unroll
                for (int o = 32; o; o >>= 1) {
                    const double ov = __shfl_xor(bv, o, 64);
                    const int    oi = __shfl_xor(bi, o, 64);
                    if (ov > bv || (ov == bv && oi < bi)) { bv = ov; bi = oi; }
                }
                bw[k] = bv; ik[k] = bi;
                if (tid == bi) v = -1.0e300;
            }
            float wk[8]; float denom = 1e-20f;
            #pragma unroll
            for (int k = 0; k < 8; ++k) {
                wk[k] = __expf((float)bw[k] - m) * inv_s; denom += wk[k];
            }
            const float invd = 1.0f / denom;
            const size_t base = (size_t)tok * 8;
            const int oldtop = (int)outIdx[base];
            if (tid < 8) {
                outIdx[base + tid] = (float)ik[tid];
                outW[base + tid]   = wk[tid] * invd;
            }
            if (tid == 0 && ik[0] != oldtop) {
                atomicAdd(&wsf[NEXP + oldtop], -1.0f);
                atomicAdd(&wsf[NEXP + ik[0]],  1.0f);
            }
        }
        __syncthreads();
    }
}

__global__ void moe_final(const float* __restrict__ wsf, float* __restrict__ out) {
    const int e = threadIdx.x;  // 64 threads
    float v = wsf[e] * wsf[NEXP + e];
    #pragma unroll
    for (int o = 32; o; o >>= 1) v += __shfl_xor(v, o, 64);
    if (e == 0)
        out[2 * TOKS * 8] = v * (64.0f / ((float)TOKS * (float)TOKS));
}

// ===== fallback monolith (proven R2 path) for small ws =====
__global__ void moe_init(float* __restrict__ wsf, int n) {
    const int i = blockIdx.x * blockDim.x + threadIdx.x;
    if (i < n) wsf[i] = 0.0f;
}

__global__ void moe_w_cvt(const float* __restrict__ W, double* __restrict__ Wd) {
    const int i = blockIdx.x * blockDim.x + threadIdx.x;
    if (i < NEXP * HID) Wd[i] = (double)W[i];
}

__global__ __launch_bounds__(512, 2)
void moe_mono(const float* __restrict__ X, const double* __restrict__ Wd,
              float* __restrict__ out, float* __restrict__ wsf) {
    __shared__ double xs[64][66];
    __shared__ double L2[64][65];
    const int tid  = threadIdx.x;
    const int lane = tid & 63;
    const int wid  = __builtin_amdgcn_readfirstlane(tid >> 6);
    const int tok0 = blockIdx.x * 64;
    double acc[8] = {0., 0., 0., 0., 0., 0., 0., 0.};
    for (int h0 = 0; h0 < HID; h0 += 64) {
        #pragma unroll
        for (int i = 0; i < 8; ++i) {
            const int li = tid + i * 512;
            xs[li >> 6][li & 63] = (double)X[((size_t)(tok0 + (li >> 6)) << 12) + (h0 + (li & 63))];
        }
        __syncthreads();
        const double* wchunk = Wd + (((size_t)(wid << 3)) << 12) + h0;
        #pragma unroll 2
        for (int hh = 0; hh < 64; hh += 2) {
            const double2 xv = *(const double2*)&xs[lane][hh];
            #pragma unroll
            for (int e = 0; e < 8; ++e) {
                const double* wr = wchunk + (((size_t)e) << 12) + hh;
                acc[e] = fma(xv.x, wr[0], acc[e]);
                acc[e] = fma(xv.y, wr[1], acc[e]);
            }
        }
        __syncthreads();
    }
    #pragma unroll
    for (int e = 0; e < 8; ++e) L2[lane][(wid << 3) + e] = acc[e];
    __syncthreads();
    float* outIdx = out;
    float* outW   = out + (TOKS * 8);
    float rp = 0.0f;
    for (int tt = 0; tt < 8; ++tt) {
        const int t = (wid << 3) + tt;
        const double lg = L2[t][lane];
        const float lgf = (float)lg;
        float m = lgf;
        #pragma unroll
        for (int o = 32; o; o >>= 1) m = fmaxf(m, __shfl_xor(m, o, 64));
        const float p = __expf(lgf - m);
        float s = p;
        #pragma unroll
        for (int o = 32; o; o >>= 1) s += __shfl_xor(s, o, 64);
        const float inv_s = 1.0f / s;
        rp += p * inv_s;
        double v = lg;
        float wk[8]; int ik[8];
        #pragma unroll
        for (int k = 0; k < 8; ++k) {
            double bv = v; int bi = lane;
            #pragma unroll
            for (int o = 32; o; o >>= 1) {
                const double ov = __shfl_xor(bv, o, 64);
                const int    oi = __shfl_xor(bi, o, 64);
                if (ov > bv || (ov == bv && oi < bi)) { bv = ov; bi = oi; }
            }
            wk[k] = __expf((float)bv - m) * inv_s; ik[k] = bi;
            if (lane == bi) v = -1.0e300;
        }
        if (lane == 0) {
            const float denom = (((wk[0]+wk[1])+(wk[2]+wk[3])) +
                                 ((wk[4]+wk[5])+(wk[6]+wk[7]))) + 1e-20f;
            const float invd = 1.0f / denom;
            const size_t base = ((size_t)(tok0 + t)) << 3;
            #pragma unroll
            for (int k = 0; k < 8; ++k) {
                outIdx[base + k] = (float)ik[k];
                outW[base + k]   = wk[k] * invd;
            }
            atomicAdd(&wsf[NEXP + ik[0]], 1.0f);
        }
    }
    atomicAdd(&wsf[lane], rp);
}

extern "C" void kernel_launch(void* const* d_in, const int* in_sizes, int n_in,
                              void* d_out, int out_size, void* d_ws, size_t ws_size,
                              hipStream_t stream) {
    const float* X = (const float*)d_in[0];   // [4,4096,4096] fp32
    const float* W = (const float*)d_in[1];   // [64,4096] fp32
    float* out = (float*)d_out;
    float* wsf = (float*)d_ws;

    const size_t need = 4ull * ((size_t)WS_XLO + 33554432ull);  // ~270 MB

    if (ws_size >= need) {
        unsigned short* Bpk = (unsigned short*)(wsf + WS_BPACK);
        unsigned short* Xhi = (unsigned short*)(wsf + WS_XHI);
        unsigned short* Xlo = (unsigned short*)(wsf + WS_XLO);
        moe_prep<<<(NEXP * HID + 255) / 256, 256, 0, stream>>>(W, Bpk, wsf);
        moe_xcvt<<<TOKS * HID / 4 / 256, 256, 0, stream>>>(X, Xhi, Xlo);
        moe_fused<<<TOKS / 64, 768, 0, stream>>>(Xhi, Xlo, Bpk, out, wsf);
        moe_fix<<<256, 256, 0, stream>>>(X, W, out, wsf);
        moe_final<<<1, 64, 0, stream>>>(wsf, out);
    } else {
        double* Wd = (double*)d_ws;
        float* wsf2 = (float*)(Wd + NEXP * HID);
        moe_w_cvt<<<(NEXP * HID + 255) / 256, 256, 0, stream>>>(W, Wd);
        moe_init<<<1, 256, 0, stream>>>(wsf2, 128);
        moe_mono<<<TOKS / 64, 512, 0, stream>>>(X, Wd, out, wsf2);
        moe_final<<<1, 64, 0, stream>>>(wsf2, out);
    }
}

// Round 23
// 229.495 us; speedup vs baseline: 1.3447x; 1.3447x over previous
//
#include <hip/hip_runtime.h>
#include <hip/hip_bf16.h>

#define TOKS 16384
#define HID  4096
#define NEXP 64
#define EPS  1e-4f   // flag threshold; trunc-split logit err ~6e-6 -> 16x margin

// ===== ws layout (floats) =====
// [0..63] prob sums | [64..127] argmax counts | int@[128] flag count |
// ints [192..192+16384) flag list | [16576) Bpack (1 MB, bf16 hi/lo per (kt,nt))
#define WS_FLAGCNT  128
#define WS_FLAGLIST 192
#define WS_BPACK    16576

typedef __attribute__((ext_vector_type(8))) short short8_t;
typedef __attribute__((ext_vector_type(4))) float f32x4;

static __device__ __forceinline__ unsigned short f2bf_rn(float x) {
    unsigned u = __builtin_bit_cast(unsigned, x);
    u = (u + 0x7fffu + ((u >> 16) & 1u)) >> 16;
    return (unsigned short)u;
}
static __device__ __forceinline__ float bf2f(unsigned short h) {
    return __builtin_bit_cast(float, (unsigned)h << 16);
}
static __device__ __forceinline__ void gl2lds16(const void* g, void* l) {
    __builtin_amdgcn_global_load_lds(
        (const __attribute__((address_space(1))) unsigned int*)g,
        (__attribute__((address_space(3))) unsigned int*)l, 16, 0, 0);
}
// truncation split packers: 8 floats -> 8 hi bf16 (uint4) / 8 lo bf16 (uint4)
static __device__ __forceinline__ uint4 hipack(float4 a, float4 b) {
    uint4 h;
    h.x = (__builtin_bit_cast(unsigned, a.y) & 0xFFFF0000u) | (__builtin_bit_cast(unsigned, a.x) >> 16);
    h.y = (__builtin_bit_cast(unsigned, a.w) & 0xFFFF0000u) | (__builtin_bit_cast(unsigned, a.z) >> 16);
    h.z = (__builtin_bit_cast(unsigned, b.y) & 0xFFFF0000u) | (__builtin_bit_cast(unsigned, b.x) >> 16);
    h.w = (__builtin_bit_cast(unsigned, b.w) & 0xFFFF0000u) | (__builtin_bit_cast(unsigned, b.z) >> 16);
    return h;
}
static __device__ __forceinline__ unsigned lo1(float x) {
    const float hif = __builtin_bit_cast(float, __builtin_bit_cast(unsigned, x) & 0xFFFF0000u);
    return __builtin_bit_cast(unsigned, x - hif) >> 16;
}
static __device__ __forceinline__ uint4 lopack(float4 a, float4 b) {
    uint4 l;
    l.x = (lo1(a.y) << 16) | lo1(a.x);
    l.y = (lo1(a.w) << 16) | lo1(a.z);
    l.z = (lo1(b.y) << 16) | lo1(b.x);
    l.w = (lo1(b.w) << 16) | lo1(b.z);
    return l;
}

// ---------- prep: W -> frag-packed bf16; (kt,nt) block = 2 KB: hi 1 KB | lo 1 KB ----------
__global__ void moe_prep(const float* __restrict__ W, unsigned short* __restrict__ Bpk,
                         float* __restrict__ wsf) {
    const int idx = blockIdx.x * blockDim.x + threadIdx.x;
    if (idx < 192) wsf[idx] = 0.0f;
    if (idx >= NEXP * HID) return;
    const int n = idx >> 12;
    const int k = idx & 4095;
    const float w = W[idx];
    const unsigned short hi = f2bf_rn(w);
    const unsigned short lo = f2bf_rn(w - bf2f(hi));
    const int kt   = k >> 5;
    const int nt   = n >> 4;
    const int lane = (n & 15) | (((k >> 3) & 3) << 4);
    const int j    = k & 7;
    const int dst  = (((kt << 2) + nt) << 10) + (lane << 3) + j;
    Bpk[dst]       = hi;
    Bpk[dst + 512] = lo;
}

// ---------- fused: producer-side cvt, cvt-FREE consumer (R22's proven 175 us side) ----------
// 256 blocks x 768 thr: waves 8..11 producers (reg-stage X fp32 -> trunc-split ->
// ds_write hi/lo columns; gl_lds B), waves 0..7 consumers (pure ds_read + MFMA).
// X read ONCE as fp32 (no prepass). 4-deep LDS (X 16K + B 16K per buf = 128 KB),
// vmcnt(8) per step (4 X-reg loads + 4 B gl_lds per stage), 1 s_barrier per step.
__global__ __launch_bounds__(768, 1)
void moe_fused(const float* __restrict__ X, const unsigned short* __restrict__ Bpk,
               float* __restrict__ out, float* __restrict__ wsf) {
    __shared__ __align__(16) char xbuf[4][16384];  // [0,8K) hi cols, [8K,16K) lo cols
    __shared__ __align__(16) char bbuf[4][16384];  // 16 x 1 KB (ktl,nt,plane)
    float (*L)[68] = (float (*)[68])&xbuf[0][0];   // epilogue alias (17408 B)

    const int tid  = threadIdx.x;
    const int lane = tid & 63;
    const int w    = tid >> 6;                 // 0..11
    const int tok0 = blockIdx.x * 64;

    f32x4 acc[2];
    acc[0] = (f32x4){0.f, 0.f, 0.f, 0.f};
    acc[1] = (f32x4){0.f, 0.f, 0.f, 0.f};

    if (w >= 8) {
        // ================= PRODUCER (reg-staged convert) =================
        const int p = w - 8;                   // 0..3
        const int r = (p << 4) + (lane >> 2);  // row 0..63 (16 rows per producer)
        const int q = lane & 3;                // k-quarter: 16 floats = chunks 2q,2q+1
        const size_t xoff = (size_t)(tok0 + r) * HID + (q << 4);
        const char* BpkB = (const char*)Bpk;
        float4 ra0, ra1, ra2, ra3, rb0, rb1, rb2, rb3;

        #define LOADA(ss) { const float* s_ = X + xoff + ((size_t)(ss) << 6);          \
            ra0 = *(const float4*)(s_);      ra1 = *(const float4*)(s_ + 4);           \
            ra2 = *(const float4*)(s_ + 8);  ra3 = *(const float4*)(s_ + 12); }
        #define LOADB(ss) { const float* s_ = X + xoff + ((size_t)(ss) << 6);          \
            rb0 = *(const float4*)(s_);      rb1 = *(const float4*)(s_ + 4);           \
            rb2 = *(const float4*)(s_ + 8);  rb3 = *(const float4*)(s_ + 12); }
        #define GLB(bf, ss) { _Pragma("unroll") for (int j = 0; j < 4; ++j) {          \
            const int c1k = (p << 2) + j;                                              \
            gl2lds16(BpkB + ((size_t)(ss) << 14) + (c1k << 10) + (lane << 4),          \
                     (void*)(&bbuf[bf][0] + (c1k << 10))); } }
        #define CVTW(f0, f1, f2, f3, bf) { char* xb = &xbuf[bf][0];                    \
            *(uint4*)(xb + ((q << 1) << 10) + (r << 4))              = hipack(f0, f1); \
            *(uint4*)(xb + 8192 + ((q << 1) << 10) + (r << 4))       = lopack(f0, f1); \
            *(uint4*)(xb + (((q << 1) | 1) << 10) + (r << 4))        = hipack(f2, f3); \
            *(uint4*)(xb + 8192 + (((q << 1) | 1) << 10) + (r << 4)) = lopack(f2, f3); }

        LOADA(0); GLB(0, 0);                   // stage 0: 4 X-reg + 4 B = 8 events
        LOADB(1); GLB(1, 1);                   // stage 1
        asm volatile("s_waitcnt vmcnt(8)" ::: "memory");   // drain stage 0
        CVTW(ra0, ra1, ra2, ra3, 0);
        asm volatile("s_waitcnt lgkmcnt(0)" ::: "memory");

        #pragma unroll 2
        for (int s = 0; s < 64; ++s) {
            const int ss = (s + 2 < 64) ? (s + 2) : 63;    // tail dups -> dead bufs
            if ((s & 1) == 0) { LOADA(ss); } else { LOADB(ss); }
            GLB((s + 2) & 3, ss);
            asm volatile("s_waitcnt vmcnt(8)" ::: "memory"); // drain stage s+1
            if ((s & 1) == 0) { CVTW(rb0, rb1, rb2, rb3, (s + 1) & 3); }
            else              { CVTW(ra0, ra1, ra2, ra3, (s + 1) & 3); }
            asm volatile("s_waitcnt lgkmcnt(0)" ::: "memory");
            __builtin_amdgcn_s_barrier();
        }
        asm volatile("s_waitcnt vmcnt(0)" ::: "memory");
        #undef LOADA
        #undef LOADB
        #undef GLB
        #undef CVTW
    } else {
        // ================= CONSUMER (ZERO VALU in loop: ds_read + MFMA only) =========
        const int mt = w & 3;                  // m-tile (16 tokens)
        const int nh = w >> 2;                 // n-half (2 ntiles)
        const int g  = lane >> 4;
        const int arow16 = (((mt << 4) + (lane & 15)) << 4);  // row * 16 B
        for (int s = 0; s < 64; ++s) {
            __builtin_amdgcn_s_barrier();
            __builtin_amdgcn_sched_barrier(0);
            const int cur = s & 3;
            const char* xb = &xbuf[cur][0];
            const char* bb = &bbuf[cur][0];
            #pragma unroll
            for (int ktl = 0; ktl < 2; ++ktl) {
                const int cpos = ((ktl << 2) + g) << 10;      // chunk column base
                const short8_t ah = *(const short8_t*)(xb + cpos + arow16);
                const short8_t al = *(const short8_t*)(xb + 8192 + cpos + arow16);
                #pragma unroll
                for (int ntl = 0; ntl < 2; ++ntl) {
                    const char* bp = bb + (((ktl << 2) + (nh << 1) + ntl) << 11) + (lane << 4);
                    const short8_t bh = *(const short8_t*)bp;
                    const short8_t bl = *(const short8_t*)(bp + 1024);
                    acc[ntl] = __builtin_amdgcn_mfma_f32_16x16x32_bf16(ah, bh, acc[ntl], 0, 0, 0);
                    acc[ntl] = __builtin_amdgcn_mfma_f32_16x16x32_bf16(al, bh, acc[ntl], 0, 0, 0);
                    acc[ntl] = __builtin_amdgcn_mfma_f32_16x16x32_bf16(ah, bl, acc[ntl], 0, 0, 0);
                }
            }
            __builtin_amdgcn_sched_barrier(0);
        }
    }
    __syncthreads();   // all 12 waves

    // ---- logits -> L[token][expert] (L aliases xbuf; consumers only) ----
    if (w < 8) {
        const int mt = w & 3, nh = w >> 2, g = lane >> 4;
        #pragma unroll
        for (int ntl = 0; ntl < 2; ++ntl)
            #pragma unroll
            for (int rr = 0; rr < 4; ++rr)
                L[(mt << 4) + (g << 2) + rr][(nh << 5) + (ntl << 4) + (lane & 15)] = acc[ntl][rr];
    }
    __syncthreads();

    // ---- epilogue: consumer wave w handles tokens w*8 .. w*8+7; lane = expert ----
    float* outIdx = out;
    float* outW   = out + TOKS * 8;
    int* flagcnt  = (int*)wsf + WS_FLAGCNT;
    int* flaglist = (int*)wsf + WS_FLAGLIST;

    if (w < 8) {
        float rp = 0.f;
        #pragma unroll
        for (int tt = 0; tt < 8; ++tt) {
            const int tl = (w << 3) + tt;
            const float lg = L[tl][lane];

            // bitonic sort-64, descending by (value, then lower index first)
            float v = lg; int idx = lane;
            #pragma unroll
            for (int size = 2; size <= 64; size <<= 1) {
                #pragma unroll
                for (int str = size >> 1; str > 0; str >>= 1) {
                    const float ov = __shfl_xor(v, str, 64);
                    const int   oi = __shfl_xor(idx, str, 64);
                    const bool pb = (ov > v) || (ov == v && oi < idx);
                    const bool keepFirst = ((lane & str) == 0) == ((lane & size) == 0);
                    if (pb == keepFirst) { v = ov; idx = oi; }
                }
            }

            const float m = __shfl(v, 0, 64);
            const float p = __expf(lg - m);
            float sdenom = p;
            #pragma unroll
            for (int o = 32; o; o >>= 1) sdenom += __shfl_xor(sdenom, o, 64);
            const float inv_s = 1.0f / sdenom;
            rp += p * inv_s;

            const float wkv = __expf(v - m) * inv_s;
            float d8 = (lane < 8) ? wkv : 0.f;
            #pragma unroll
            for (int o = 1; o < 8; o <<= 1) d8 += __shfl_xor(d8, o, 64);
            const float invd = 1.0f / (d8 + 1e-20f);
            const float nv = __shfl_down(v, 1, 64);
            const bool flg = __any(lane < 8 && (v - nv) < EPS);

            const int gtok = tok0 + tl;
            if (lane < 8) {
                outIdx[(size_t)gtok * 8 + lane] = (float)idx;
                outW[(size_t)gtok * 8 + lane]   = wkv * invd;
            }
            if (lane == 0) {
                atomicAdd(&wsf[NEXP + idx], 1.0f);
                if (flg) {
                    const int pos = atomicAdd(flagcnt, 1);
                    if (pos < TOKS) flaglist[pos] = gtok;
                }
            }
        }
        atomicAdd(&wsf[lane], rp);
    }
}

// ---------- exact fp64 redo for flagged tokens (reads original fp32 X) ----------
__global__ __launch_bounds__(256, 2)
void moe_fix(const float* __restrict__ X, const float* __restrict__ W,
             float* __restrict__ out, float* __restrict__ wsf) {
    __shared__ double red[256];
    const int tid = threadIdx.x;
    const int e   = tid & 63;
    const int kc  = tid >> 6;
    const int nf  = min(*((int*)wsf + WS_FLAGCNT), TOKS);
    const int* flaglist = (const int*)wsf + WS_FLAGLIST;
    float* outIdx = out;
    float* outW   = out + TOKS * 8;

    for (int fi = blockIdx.x; fi < nf; fi += gridDim.x) {
        const int tok = flaglist[fi];
        const float* xrow = X + (size_t)tok * HID + kc * 1024;
        const float* wrow = W + (size_t)e  * HID + kc * 1024;
        double part = 0.0;
        for (int j = 0; j < 1024; j += 4) {
            const float4 xv = *(const float4*)(xrow + j);
            const float4 wv = *(const float4*)(wrow + j);
            part = fma((double)xv.x, (double)wv.x, part);
            part = fma((double)xv.y, (double)wv.y, part);
            part = fma((double)xv.z, (double)wv.z, part);
            part = fma((double)xv.w, (double)wv.w, part);
        }
        red[tid] = part;
        __syncthreads();
        if (tid < 64) {
            const double lg = ((red[tid] + red[64 + tid]) + red[128 + tid]) + red[192 + tid];
            const float lgf = (float)lg;
            float m = lgf;
            #pragma unroll
            for (int o = 32; o; o >>= 1) m = fmaxf(m, __shfl_xor(m, o, 64));
            const float p = __expf(lgf - m);
            float s = p;
            #pragma unroll
            for (int o = 32; o; o >>= 1) s += __shfl_xor(s, o, 64);
            const float inv_s = 1.0f / s;

            double v = lg;
            double bw[8]; int ik[8];
            #pragma unroll
            for (int k = 0; k < 8; ++k) {
                double bv = v; int bi = tid;
                #pragma unroll
                for (int o = 32; o; o >>= 1) {
                    const double ov = __shfl_xor(bv, o, 64);
                    const int    oi = __shfl_xor(bi, o, 64);
                    if (ov > bv || (ov == bv && oi < bi)) { bv = ov; bi = oi; }
                }
                bw[k] = bv; ik[k] = bi;
                if (tid == bi) v = -1.0e300;
            }
            float wk[8]; float denom = 1e-20f;
            #pragma unroll
            for (int k = 0; k < 8; ++k) {
                wk[k] = __expf((float)bw[k] - m) * inv_s; denom += wk[k];
            }
            const float invd = 1.0f / denom;
            const size_t base = (size_t)tok * 8;
            const int oldtop = (int)outIdx[base];
            if (tid < 8) {
                outIdx[base + tid] = (float)ik[tid];
                outW[base + tid]   = wk[tid] * invd;
            }
            if (tid == 0 && ik[0] != oldtop) {
                atomicAdd(&wsf[NEXP + oldtop], -1.0f);
                atomicAdd(&wsf[NEXP + ik[0]],  1.0f);
            }
        }
        __syncthreads();
    }
}

__global__ void moe_final(const float* __restrict__ wsf, float* __restrict__ out) {
    const int e = threadIdx.x;  // 64 threads
    float v = wsf[e] * wsf[NEXP + e];
    #pragma unroll
    for (int o = 32; o; o >>= 1) v += __shfl_xor(v, o, 64);
    if (e == 0)
        out[2 * TOKS * 8] = v * (64.0f / ((float)TOKS * (float)TOKS));
}

// ===== fallback monolith (proven R2 path) for small ws =====
__global__ void moe_init(float* __restrict__ wsf, int n) {
    const int i = blockIdx.x * blockDim.x + threadIdx.x;
    if (i < n) wsf[i] = 0.0f;
}

__global__ void moe_w_cvt(const float* __restrict__ W, double* __restrict__ Wd) {
    const int i = blockIdx.x * blockDim.x + threadIdx.x;
    if (i < NEXP * HID) Wd[i] = (double)W[i];
}

__global__ __launch_bounds__(512, 2)
void moe_mono(const float* __restrict__ X, const double* __restrict__ Wd,
              float* __restrict__ out, float* __restrict__ wsf) {
    __shared__ double xs[64][66];
    __shared__ double L2[64][65];
    const int tid  = threadIdx.x;
    const int lane = tid & 63;
    const int wid  = __builtin_amdgcn_readfirstlane(tid >> 6);
    const int tok0 = blockIdx.x * 64;
    double acc[8] = {0., 0., 0., 0., 0., 0., 0., 0.};
    for (int h0 = 0; h0 < HID; h0 += 64) {
        #pragma unroll
        for (int i = 0; i < 8; ++i) {
            const int li = tid + i * 512;
            xs[li >> 6][li & 63] = (double)X[((size_t)(tok0 + (li >> 6)) << 12) + (h0 + (li & 63))];
        }
        __syncthreads();
        const double* wchunk = Wd + (((size_t)(wid << 3)) << 12) + h0;
        #pragma unroll 2
        for (int hh = 0; hh < 64; hh += 2) {
            const double2 xv = *(const double2*)&xs[lane][hh];
            #pragma unroll
            for (int e = 0; e < 8; ++e) {
                const double* wr = wchunk + (((size_t)e) << 12) + hh;
                acc[e] = fma(xv.x, wr[0], acc[e]);
                acc[e] = fma(xv.y, wr[1], acc[e]);
            }
        }
        __syncthreads();
    }
    #pragma unroll
    for (int e = 0; e < 8; ++e) L2[lane][(wid << 3) + e] = acc[e];
    __syncthreads();
    float* outIdx = out;
    float* outW   = out + (TOKS * 8);
    float rp = 0.0f;
    for (int tt = 0; tt < 8; ++tt) {
        const int t = (wid << 3) + tt;
        const double lg = L2[t][lane];
        const float lgf = (float)lg;
        float m = lgf;
        #pragma unroll
        for (int o = 32; o; o >>= 1) m = fmaxf(m, __shfl_xor(m, o, 64));
        const float p = __expf(lgf - m);
        float s = p;
        #pragma unroll
        for (int o = 32; o; o >>= 1) s += __shfl_xor(s, o, 64);
        const float inv_s = 1.0f / s;
        rp += p * inv_s;
        double v = lg;
        float wk[8]; int ik[8];
        #pragma unroll
        for (int k = 0; k < 8; ++k) {
            double bv = v; int bi = lane;
            #pragma unroll
            for (int o = 32; o; o >>= 1) {
                const double ov = __shfl_xor(bv, o, 64);
                const int    oi = __shfl_xor(bi, o, 64);
                if (ov > bv || (ov == bv && oi < bi)) { bv = ov; bi = oi; }
            }
            wk[k] = __expf((float)bv - m) * inv_s; ik[k] = bi;
            if (lane == bi) v = -1.0e300;
        }
        if (lane == 0) {
            const float denom = (((wk[0]+wk[1])+(wk[2]+wk[3])) +
                                 ((wk[4]+wk[5])+(wk[6]+wk[7]))) + 1e-20f;
            const float invd = 1.0f / denom;
            const size_t base = ((size_t)(tok0 + t)) << 3;
            #pragma unroll
            for (int k = 0; k < 8; ++k) {
                outIdx[base + k] = (float)ik[k];
                outW[base + k]   = wk[k] * invd;
            }
            atomicAdd(&wsf[NEXP + ik[0]], 1.0f);
        }
    }
    atomicAdd(&wsf[lane], rp);
}

extern "C" void kernel_launch(void* const* d_in, const int* in_sizes, int n_in,
                              void* d_out, int out_size, void* d_ws, size_t ws_size,
                              hipStream_t stream) {
    const float* X = (const float*)d_in[0];   // [4,4096,4096] fp32
    const float* W = (const float*)d_in[1];   // [64,4096] fp32
    float* out = (float*)d_out;
    float* wsf = (float*)d_ws;

    const size_t need = 4ull * WS_BPACK + 2ull * 524288;  // slots + Bpack ~ 1.1 MB

    if (ws_size >= need) {
        unsigned short* Bpk = (unsigned short*)(wsf + WS_BPACK);
        moe_prep<<<(NEXP * HID + 255) / 256, 256, 0, stream>>>(W, Bpk, wsf);
        moe_fused<<<TOKS / 64, 768, 0, stream>>>(X, Bpk, out, wsf);
        moe_fix<<<256, 256, 0, stream>>>(X, W, out, wsf);
        moe_final<<<1, 64, 0, stream>>>(wsf, out);
    } else {
        double* Wd = (double*)d_ws;
        float* wsf2 = (float*)(Wd + NEXP * HID);
        moe_w_cvt<<<(NEXP * HID + 255) / 256, 256, 0, stream>>>(W, Wd);
        moe_init<<<1, 256, 0, stream>>>(wsf2, 128);
        moe_mono<<<TOKS / 64, 512, 0, stream>>>(X, Wd, out, wsf2);
        moe_final<<<1, 64, 0, stream>>>(wsf2, out);
    }
}

// Round 24
// 204.541 us; speedup vs baseline: 1.5088x; 1.1220x over previous
//
#include <hip/hip_runtime.h>
#include <hip/hip_bf16.h>

#define TOKS 16384
#define HID  4096
#define NEXP 64
#define EPS  1e-4f   // flag threshold; trunc-split logit err ~6e-6 -> 16x margin

// ===== ws layout (floats) =====
// [0..63] prob sums | [64..127] argmax counts | int@[128] flag count |
// ints [192..192+16384) flag list | [16576) Bpack (1 MB, bf16 hi/lo per (kt,nt))
#define WS_FLAGCNT  128
#define WS_FLAGLIST 192
#define WS_BPACK    16576

typedef __attribute__((ext_vector_type(8))) short short8_t;
typedef __attribute__((ext_vector_type(4))) float f32x4;

static __device__ __forceinline__ unsigned short f2bf_rn(float x) {
    unsigned u = __builtin_bit_cast(unsigned, x);
    u = (u + 0x7fffu + ((u >> 16) & 1u)) >> 16;
    return (unsigned short)u;
}
static __device__ __forceinline__ float bf2f(unsigned short h) {
    return __builtin_bit_cast(float, (unsigned)h << 16);
}
static __device__ __forceinline__ void gl2lds16(const void* g, void* l) {
    __builtin_amdgcn_global_load_lds(
        (const __attribute__((address_space(1))) unsigned int*)g,
        (__attribute__((address_space(3))) unsigned int*)l, 16, 0, 0);
}

// ---------- prep: W -> frag-packed bf16; (kt,nt) block = 2 KB: hi 1 KB | lo 1 KB ----------
// u16 index: (kt*4+nt)*1024 + plane*512 + lane*8 + j ; lane=(n&15)|(((k>>3)&3)<<4), j=k&7
__global__ void moe_prep(const float* __restrict__ W, unsigned short* __restrict__ Bpk,
                         float* __restrict__ wsf) {
    const int idx = blockIdx.x * blockDim.x + threadIdx.x;
    if (idx < 192) wsf[idx] = 0.0f;
    if (idx >= NEXP * HID) return;
    const int n = idx >> 12;
    const int k = idx & 4095;
    const float w = W[idx];
    const unsigned short hi = f2bf_rn(w);
    const unsigned short lo = f2bf_rn(w - bf2f(hi));
    const int kt   = k >> 5;
    const int nt   = n >> 4;
    const int lane = (n & 15) | (((k >> 3) & 3) << 4);
    const int j    = k & 7;
    const int dst  = (((kt << 2) + nt) << 10) + (lane << 3) + j;
    Bpk[dst]       = hi;
    Bpk[dst + 512] = lo;
}

// ---------- fused: PRODUCER/CONSUMER wave-specialized MFMA GEMM + epilogue ----------
// 256 blocks x 768 thr (12 waves): waves 8..11 = PRODUCERS (pure gl_lds loop, the
// R17-probe structure that measured 3.2 TB/s); waves 0..7 = CONSUMERS (R12 compute,
// ZERO VMEM instructions in the loop). 4-deep 128 KB LDS, one s_barrier per step.
// Producer iter s: issue stage(s+2), vmcnt(8) [stage s+1 drained, s+2 in flight],
// barrier. Consumer iter s: barrier, compute buf s&3. Writer (s+2)&3 vs reader s&3.
__global__ __launch_bounds__(768, 1)
void moe_fused(const float* __restrict__ X, const unsigned short* __restrict__ Bpk,
               float* __restrict__ out, float* __restrict__ wsf) {
    __shared__ __align__(16) char xbuf[4][16384];  // X: 64 rows x 256 B, src-XOR-swz
    __shared__ __align__(16) char bbuf[4][16384];  // B: (ktl,nt) 2 KB blocks (hi|lo)
    float (*L)[68] = (float (*)[68])&xbuf[0][0];   // epilogue alias (17408 B)

    const int tid  = threadIdx.x;
    const int lane = tid & 63;
    const int w    = tid >> 6;                 // 0..11
    const int tok0 = blockIdx.x * 64;

    f32x4 acc[2];
    acc[0] = (f32x4){0.f, 0.f, 0.f, 0.f};
    acc[1] = (f32x4){0.f, 0.f, 0.f, 0.f};

    if (w >= 8) {
        // ================= PRODUCER (probe-proven structure) =================
        const int p = w - 8;                   // 0..3
        size_t xsrc[4]; int xdst[4];
        #pragma unroll
        for (int j = 0; j < 4; ++j) {          // X instr i=p*4+j covers rows 4i..4i+3
            const int i  = (p << 2) + j;
            const int rg = (i << 2) + (lane >> 4);
            const int ck = (lane & 15) ^ (rg & 15);    // R12-proven src-XOR swizzle
            xsrc[j] = (size_t)(tok0 + rg) * HID + (ck << 2);
            xdst[j] = i << 10;
        }
        const char* BpkB = (const char*)Bpk;
        #define PSTAGE(bf, ss)                                                         \
        {                                                                              \
            const int k0_ = (ss) << 6;                                                 \
            _Pragma("unroll")                                                          \
            for (int j = 0; j < 4; ++j)                                                \
                gl2lds16(X + xsrc[j] + k0_, (void*)(&xbuf[bf][0] + xdst[j]));          \
            _Pragma("unroll")                                                          \
            for (int j = 0; j < 4; ++j) {                                              \
                const int c1k = (p << 2) + j;                                          \
                gl2lds16(BpkB + ((size_t)(ss) << 14) + (c1k << 10) + (lane << 4),      \
                         (void*)(&bbuf[bf][0] + (c1k << 10)));                         \
            }                                                                          \
        }
        PSTAGE(0, 0);
        PSTAGE(1, 1);
        for (int s = 0; s < 64; ++s) {
            const int ss = (s + 2 < 64) ? (s + 2) : 63;   // tail dups land in dead bufs
            PSTAGE((s + 2) & 3, ss);
            asm volatile("s_waitcnt vmcnt(8)" ::: "memory");  // stage s+1 drained
            __builtin_amdgcn_s_barrier();
        }
        asm volatile("s_waitcnt vmcnt(0)" ::: "memory");
        #undef PSTAGE
    } else {
        // ================= CONSUMER (R12-proven compute, no VMEM) =================
        const int mt = w & 3;                  // m-tile (16 tokens)
        const int nh = w >> 2;                 // n-half (2 ntiles)
        const int g  = lane >> 4;
        const int tr = (mt << 4) + (lane & 15);
        const int rsw = lane & 15;
        for (int s = 0; s < 64; ++s) {
            __builtin_amdgcn_s_barrier();
            __builtin_amdgcn_sched_barrier(0);
            const int cur = s & 3;
            const char* ab = &xbuf[cur][0] + (tr << 8);
            const char* bb = &bbuf[cur][0];
            #pragma unroll
            for (int ktl = 0; ktl < 2; ++ktl) {
                const int cl = (ktl << 3) + (g << 1);
                const float4 a0 = *(const float4*)(ab + ((cl ^ rsw) << 4));
                const float4 a1 = *(const float4*)(ab + (((cl + 1) ^ rsw) << 4));
                const float xv[8] = {a0.x, a0.y, a0.z, a0.w, a1.x, a1.y, a1.z, a1.w};
                short8_t ah, al;
                #pragma unroll
                for (int j = 0; j < 8; ++j) {  // exact trunc split: x = hif + lof
                    const unsigned u = __builtin_bit_cast(unsigned, xv[j]);
                    ah[j] = (short)(u >> 16);
                    const float hif = __builtin_bit_cast(float, u & 0xFFFF0000u);
                    al[j] = (short)(__builtin_bit_cast(unsigned, xv[j] - hif) >> 16);
                }
                #pragma unroll
                for (int ntl = 0; ntl < 2; ++ntl) {
                    const char* bp = bb + (((ktl << 2) + (nh << 1) + ntl) << 11) + (lane << 4);
                    const short8_t bh = *(const short8_t*)bp;
                    const short8_t bl = *(const short8_t*)(bp + 1024);
                    acc[ntl] = __builtin_amdgcn_mfma_f32_16x16x32_bf16(ah, bh, acc[ntl], 0, 0, 0);
                    acc[ntl] = __builtin_amdgcn_mfma_f32_16x16x32_bf16(al, bh, acc[ntl], 0, 0, 0);
                    acc[ntl] = __builtin_amdgcn_mfma_f32_16x16x32_bf16(ah, bl, acc[ntl], 0, 0, 0);
                }
            }
            __builtin_amdgcn_sched_barrier(0);
        }
    }
    __syncthreads();   // all 12 waves; drains producer LDS writes

    // ---- logits -> L[token][expert] (L aliases xbuf; consumers only) ----
    if (w < 8) {
        const int mt = w & 3, nh = w >> 2, g = lane >> 4;
        #pragma unroll
        for (int ntl = 0; ntl < 2; ++ntl)
            #pragma unroll
            for (int rr = 0; rr < 4; ++rr)
                L[(mt << 4) + (g << 2) + rr][(nh << 5) + (ntl << 4) + (lane & 15)] = acc[ntl][rr];
    }
    __syncthreads();

    // ---- epilogue: consumer wave w handles tokens w*8 .. w*8+7; lane = expert ----
    float* outIdx = out;
    float* outW   = out + TOKS * 8;
    int* flagcnt  = (int*)wsf + WS_FLAGCNT;
    int* flaglist = (int*)wsf + WS_FLAGLIST;

    if (w < 8) {
        float rp = 0.f;
        #pragma unroll
        for (int tt = 0; tt < 8; ++tt) {
            const int tl = (w << 3) + tt;
            const float lg = L[tl][lane];

            // bitonic sort-64, descending by (value, then lower index first)
            float v = lg; int idx = lane;
            #pragma unroll
            for (int size = 2; size <= 64; size <<= 1) {
                #pragma unroll
                for (int str = size >> 1; str > 0; str >>= 1) {
                    const float ov = __shfl_xor(v, str, 64);
                    const int   oi = __shfl_xor(idx, str, 64);
                    const bool pb = (ov > v) || (ov == v && oi < idx);
                    const bool keepFirst = ((lane & str) == 0) == ((lane & size) == 0);
                    if (pb == keepFirst) { v = ov; idx = oi; }
                }
            }

            const float m = __shfl(v, 0, 64);
            const float p = __expf(lg - m);
            float sdenom = p;
            #pragma unroll
            for (int o = 32; o; o >>= 1) sdenom += __shfl_xor(sdenom, o, 64);
            const float inv_s = 1.0f / sdenom;
            rp += p * inv_s;

            const float wkv = __expf(v - m) * inv_s;
            float d8 = (lane < 8) ? wkv : 0.f;
            #pragma unroll
            for (int o = 1; o < 8; o <<= 1) d8 += __shfl_xor(d8, o, 64);
            const float invd = 1.0f / (d8 + 1e-20f);
            const float nv = __shfl_down(v, 1, 64);
            const bool flg = __any(lane < 8 && (v - nv) < EPS);

            const int gtok = tok0 + tl;
            if (lane < 8) {
                outIdx[(size_t)gtok * 8 + lane] = (float)idx;
                outW[(size_t)gtok * 8 + lane]   = wkv * invd;
            }
            if (lane == 0) {
                atomicAdd(&wsf[NEXP + idx], 1.0f);
                if (flg) {
                    const int pos = atomicAdd(flagcnt, 1);
                    if (pos < TOKS) flaglist[pos] = gtok;
                }
            }
        }
        atomicAdd(&wsf[lane], rp);
    }
}

// ---------- exact fp64 redo for flagged tokens ----------
__global__ __launch_bounds__(256, 2)
void moe_fix(const float* __restrict__ X, const float* __restrict__ W,
             float* __restrict__ out, float* __restrict__ wsf) {
    __shared__ double red[256];
    const int tid = threadIdx.x;
    const int e   = tid & 63;
    const int kc  = tid >> 6;
    const int nf  = min(*((int*)wsf + WS_FLAGCNT), TOKS);
    const int* flaglist = (const int*)wsf + WS_FLAGLIST;
    float* outIdx = out;
    float* outW   = out + TOKS * 8;

    for (int fi = blockIdx.x; fi < nf; fi += gridDim.x) {
        const int tok = flaglist[fi];
        const float* xrow = X + (size_t)tok * HID + kc * 1024;
        const float* wrow = W + (size_t)e  * HID + kc * 1024;
        double part = 0.0;
        for (int j = 0; j < 1024; j += 4) {
            const float4 xv = *(const float4*)(xrow + j);
            const float4 wv = *(const float4*)(wrow + j);
            part = fma((double)xv.x, (double)wv.x, part);
            part = fma((double)xv.y, (double)wv.y, part);
            part = fma((double)xv.z, (double)wv.z, part);
            part = fma((double)xv.w, (double)wv.w, part);
        }
        red[tid] = part;
        __syncthreads();
        if (tid < 64) {
            const double lg = ((red[tid] + red[64 + tid]) + red[128 + tid]) + red[192 + tid];
            const float lgf = (float)lg;
            float m = lgf;
            #pragma unroll
            for (int o = 32; o; o >>= 1) m = fmaxf(m, __shfl_xor(m, o, 64));
            const float p = __expf(lgf - m);
            float s = p;
            #pragma unroll
            for (int o = 32; o; o >>= 1) s += __shfl_xor(s, o, 64);
            const float inv_s = 1.0f / s;

            double v = lg;
            double bw[8]; int ik[8];
            #pragma unroll
            for (int k = 0; k < 8; ++k) {
                double bv = v; int bi = tid;
                #pragma unroll
                for (int o = 32; o; o >>= 1) {
                    const double ov = __shfl_xor(bv, o, 64);
                    const int    oi = __shfl_xor(bi, o, 64);
                    if (ov > bv || (ov == bv && oi < bi)) { bv = ov; bi = oi; }
                }
                bw[k] = bv; ik[k] = bi;
                if (tid == bi) v = -1.0e300;
            }
            float wk[8]; float denom = 1e-20f;
            #pragma unroll
            for (int k = 0; k < 8; ++k) {
                wk[k] = __expf((float)bw[k] - m) * inv_s; denom += wk[k];
            }
            const float invd = 1.0f / denom;
            const size_t base = (size_t)tok * 8;
            const int oldtop = (int)outIdx[base];
            if (tid < 8) {
                outIdx[base + tid] = (float)ik[tid];
                outW[base + tid]   = wk[tid] * invd;
            }
            if (tid == 0 && ik[0] != oldtop) {
                atomicAdd(&wsf[NEXP + oldtop], -1.0f);
                atomicAdd(&wsf[NEXP + ik[0]],  1.0f);
            }
        }
        __syncthreads();
    }
}

__global__ void moe_final(const float* __restrict__ wsf, float* __restrict__ out) {
    const int e = threadIdx.x;  // 64 threads
    float v = wsf[e] * wsf[NEXP + e];
    #pragma unroll
    for (int o = 32; o; o >>= 1) v += __shfl_xor(v, o, 64);
    if (e == 0)
        out[2 * TOKS * 8] = v * (64.0f / ((float)TOKS * (float)TOKS));
}

// ===== fallback monolith (proven R2 path) for small ws =====
__global__ void moe_init(float* __restrict__ wsf, int n) {
    const int i = blockIdx.x * blockDim.x + threadIdx.x;
    if (i < n) wsf[i] = 0.0f;
}

__global__ void moe_w_cvt(const float* __restrict__ W, double* __restrict__ Wd) {
    const int i = blockIdx.x * blockDim.x + threadIdx.x;
    if (i < NEXP * HID) Wd[i] = (double)W[i];
}

__global__ __launch_bounds__(512, 2)
void moe_mono(const float* __restrict__ X, const double* __restrict__ Wd,
              float* __restrict__ out, float* __restrict__ wsf) {
    __shared__ double xs[64][66];
    __shared__ double L2[64][65];
    const int tid  = threadIdx.x;
    const int lane = tid & 63;
    const int wid  = __builtin_amdgcn_readfirstlane(tid >> 6);
    const int tok0 = blockIdx.x * 64;
    double acc[8] = {0., 0., 0., 0., 0., 0., 0., 0.};
    for (int h0 = 0; h0 < HID; h0 += 64) {
        #pragma unroll
        for (int i = 0; i < 8; ++i) {
            const int li = tid + i * 512;
            xs[li >> 6][li & 63] = (double)X[((size_t)(tok0 + (li >> 6)) << 12) + (h0 + (li & 63))];
        }
        __syncthreads();
        const double* wchunk = Wd + (((size_t)(wid << 3)) << 12) + h0;
        #pragma unroll 2
        for (int hh = 0; hh < 64; hh += 2) {
            const double2 xv = *(const double2*)&xs[lane][hh];
            #pragma unroll
            for (int e = 0; e < 8; ++e) {
                const double* wr = wchunk + (((size_t)e) << 12) + hh;
                acc[e] = fma(xv.x, wr[0], acc[e]);
                acc[e] = fma(xv.y, wr[1], acc[e]);
            }
        }
        __syncthreads();
    }
    #pragma unroll
    for (int e = 0; e < 8; ++e) L2[lane][(wid << 3) + e] = acc[e];
    __syncthreads();
    float* outIdx = out;
    float* outW   = out + (TOKS * 8);
    float rp = 0.0f;
    for (int tt = 0; tt < 8; ++tt) {
        const int t = (wid << 3) + tt;
        const double lg = L2[t][lane];
        const float lgf = (float)lg;
        float m = lgf;
        #pragma unroll
        for (int o = 32; o; o >>= 1) m = fmaxf(m, __shfl_xor(m, o, 64));
        const float p = __expf(lgf - m);
        float s = p;
        #pragma unroll
        for (int o = 32; o; o >>= 1) s += __shfl_xor(s, o, 64);
        const float inv_s = 1.0f / s;
        rp += p * inv_s;
        double v = lg;
        float wk[8]; int ik[8];
        #pragma unroll
        for (int k = 0; k < 8; ++k) {
            double bv = v; int bi = lane;
            #pragma unroll
            for (int o = 32; o; o >>= 1) {
                const double ov = __shfl_xor(bv, o, 64);
                const int    oi = __shfl_xor(bi, o, 64);
                if (ov > bv || (ov == bv && oi < bi)) { bv = ov; bi = oi; }
            }
            wk[k] = __expf((float)bv - m) * inv_s; ik[k] = bi;
            if (lane == bi) v = -1.0e300;
        }
        if (lane == 0) {
            const float denom = (((wk[0]+wk[1])+(wk[2]+wk[3])) +
                                 ((wk[4]+wk[5])+(wk[6]+wk[7]))) + 1e-20f;
            const float invd = 1.0f / denom;
            const size_t base = ((size_t)(tok0 + t)) << 3;
            #pragma unroll
            for (int k = 0; k < 8; ++k) {
                outIdx[base + k] = (float)ik[k];
                outW[base + k]   = wk[k] * invd;
            }
            atomicAdd(&wsf[NEXP + ik[0]], 1.0f);
        }
    }
    atomicAdd(&wsf[lane], rp);
}

extern "C" void kernel_launch(void* const* d_in, const int* in_sizes, int n_in,
                              void* d_out, int out_size, void* d_ws, size_t ws_size,
                              hipStream_t stream) {
    const float* X = (const float*)d_in[0];   // [4,4096,4096] fp32
    const float* W = (const float*)d_in[1];   // [64,4096] fp32
    float* out = (float*)d_out;
    float* wsf = (float*)d_ws;

    const size_t need = 4ull * WS_BPACK + 2ull * 524288;  // slots + Bpack ~ 1.1 MB

    if (ws_size >= need) {
        unsigned short* Bpk = (unsigned short*)(wsf + WS_BPACK);
        moe_prep<<<(NEXP * HID + 255) / 256, 256, 0, stream>>>(W, Bpk, wsf);
        moe_fused<<<TOKS / 64, 768, 0, stream>>>(X, Bpk, out, wsf);
        moe_fix<<<256, 256, 0, stream>>>(X, W, out, wsf);
        moe_final<<<1, 64, 0, stream>>>(wsf, out);
    } else {
        double* Wd = (double*)d_ws;
        float* wsf2 = (float*)(Wd + NEXP * HID);
        moe_w_cvt<<<(NEXP * HID + 255) / 256, 256, 0, stream>>>(W, Wd);
        moe_init<<<1, 256, 0, stream>>>(wsf2, 128);
        moe_mono<<<TOKS / 64, 512, 0, stream>>>(X, Wd, out, wsf2);
        moe_final<<<1, 64, 0, stream>>>(wsf2, out);
    }
}